// Round 20
// baseline (37.191 us; speedup 1.0000x reference)
//
#include <hip/hip_runtime.h>
#include <math.h>

#define B_ 4
#define C_ 32
#define H_ 256
#define W_ 256
#define HW_ (H_ * W_)
#define K_ 9
#define TX 64
#define TY 2
#define HX 66              // TX + 2
#define HY 4               // TY + 2
#define HCH (HX * HY)      // 264 halo positions (no pad)
#define NOCT 4
#define NUNITS (NOCT * HCH)   // 1056 h8 units = 16.9 KB
#define EPS_ 1e-12f

typedef _Float16 h2v __attribute__((ext_vector_type(2)));
typedef _Float16 h8v __attribute__((ext_vector_type(8)));

#if defined(__has_builtin)
#if __has_builtin(__builtin_amdgcn_fdot2)
#define HAVE_FDOT2 1
#endif
#if __has_builtin(__builtin_amdgcn_cvt_pkrtz)
#define HAVE_PKRTZ 1
#endif
#endif

static __device__ __forceinline__ h2v pk2(float a, float b) {
#if defined(HAVE_PKRTZ)
    return __builtin_bit_cast(h2v, __builtin_amdgcn_cvt_pkrtz(a, b));
#else
    h2v r = {(_Float16)a, (_Float16)b};
    return r;
#endif
}

static __device__ __forceinline__ float dot2(h2v a, h2v b, float c) {
#if defined(HAVE_FDOT2)
    return __builtin_amdgcn_fdot2(a, b, c, false);
#else
    return c + (float)a[0] * (float)b[0] + (float)a[1] * (float)b[1];
#endif
}

// R19/R16 structure reshaped 32x4 -> 64x2 tile. WHY: single-round accounting
// showed stage = ~22us for 62 MB = 2.8 TB/s (vs 6.7 TB/s memset): fu halo rows
// at TX=32 are 34 floats = 136B contiguous DRAM runs (~50% efficiency). TX=64
// makes rows 66 floats = 264B runs. Cost: halo ratio 1.59->2.06 (fetch +13%,
// partly L2-absorbed). Everything else proven: 256 thr, 2 thr/px (halves in
// one wave: px=(l&31)+32*w, half=l>>5, shfl_xor 32), h8 oct-major LDS b128
// taps, fdot2, fe as 2xh8 regs, (256,6) bounds, grid 2048 = 8 blocks/CU exact.
// Spill sentinel: WRITE_SIZE must be exactly 32768 KB.
__global__ __launch_bounds__(256, 6) void asfr_kernel(const float* __restrict__ fe,
                                                      const float* __restrict__ fu,
                                                      float* __restrict__ out) {
    __shared__ h8v lds8[NUNITS];   // 16896 B
    const int t = threadIdx.x;
    const int bx = blockIdx.x & 3;            // W_/TX = 4
    const int by = (blockIdx.x >> 2) & 127;   // H_/TY = 128
    const int b  = blockIdx.x >> 9;
    const int w0 = bx * TX, h0 = by * TY;

    const int l = t & 63;            // lane
    const int wv = t >> 6;           // wave 0..3
    const int half = l >> 5;         // channel half
    const int px = (l & 31) + 32 * wv;   // 0..127
    const int x = px & 63;
    const int y = px >> 6;
    const int c0 = half << 4;
    const int pxoff = b * (C_ * HW_) + (h0 + y) * W_ + (w0 + x);

    // staging descriptors: units u = t + j*256 (j<4), tail u = 1024 + t (t<32)
    int goff[4];
    float msk[4];
#pragma unroll
    for (int j = 0; j < 4; ++j) {
        int u = t + j * 256;
        int oct = u / HCH;
        int pos = u - oct * HCH;
        int r = pos / HX;
        int col = pos - r * HX;
        int hh = h0 - 1 + r;
        int ww = w0 - 1 + col;
        bool ok = ((unsigned)hh < (unsigned)H_) && ((unsigned)ww < (unsigned)W_);
        int hcl = hh < 0 ? 0 : (hh > H_ - 1 ? H_ - 1 : hh);
        int wcl = ww < 0 ? 0 : (ww > W_ - 1 ? W_ - 1 : ww);
        goff[j] = (oct * 8) * HW_ + hcl * W_ + wcl;
        msk[j] = ok ? 1.f : 0.f;
    }
    int goffT = 0;
    float mskT = 0.f;
    if (t < NUNITS - 1024) {   // tail: 32 units
        int u = t + 1024;
        int oct = u / HCH;     // = 3
        int pos = u - oct * HCH;
        int r = pos / HX;
        int col = pos - r * HX;
        int hh = h0 - 1 + r;
        int ww = w0 - 1 + col;
        bool ok = ((unsigned)hh < (unsigned)H_) && ((unsigned)ww < (unsigned)W_);
        int hcl = hh < 0 ? 0 : (hh > H_ - 1 ? H_ - 1 : hh);
        int wcl = ww < 0 ? 0 : (ww > W_ - 1 ? W_ - 1 : ww);
        goffT = (oct * 8) * HW_ + hcl * W_ + wcl;
        mskT = ok ? 1.f : 0.f;
    }

    // fe loads + immediate h8 conversion (fv dies before fu loads peak)
    float fv[16];
#pragma unroll
    for (int cc = 0; cc < 16; ++cc) fv[cc] = fe[pxoff + (c0 + cc) * HW_];
    h8v fe8[2];
#pragma unroll
    for (int j = 0; j < 2; ++j)
#pragma unroll
        for (int c = 0; c < 4; ++c) {
            h2v p = pk2(fv[8 * j + 2 * c], fv[8 * j + 2 * c + 1]);
            fe8[j][2 * c] = p[0];
            fe8[j][2 * c + 1] = p[1];
        }

    // ALL fu staging loads in flight (main + tail), then convert+write
    const float* fub = fu + b * (C_ * HW_);
    float s[32];
#pragma unroll
    for (int j = 0; j < 4; ++j)
#pragma unroll
        for (int c = 0; c < 8; ++c) s[8 * j + c] = fub[goff[j] + c * HW_];
    float sT[8];
    if (t < NUNITS - 1024) {
#pragma unroll
        for (int c = 0; c < 8; ++c) sT[c] = fub[goffT + c * HW_];
    }
#pragma unroll
    for (int j = 0; j < 4; ++j) {
        h8v hv;
#pragma unroll
        for (int c = 0; c < 4; ++c) {
            h2v p = pk2(s[8 * j + 2 * c] * msk[j], s[8 * j + 2 * c + 1] * msk[j]);
            hv[2 * c] = p[0];
            hv[2 * c + 1] = p[1];
        }
        lds8[t + j * 256] = hv;
    }
    if (t < NUNITS - 1024) {
        h8v hv;
#pragma unroll
        for (int c = 0; c < 4; ++c) {
            h2v p = pk2(sT[2 * c] * mskT, sT[2 * c + 1] * mskT);
            hv[2 * c] = p[0];
            hv[2 * c + 1] = p[1];
        }
        lds8[t + 1024] = hv;
    }
    __syncthreads();

    const int hc = (y + 1) * HX + (x + 1);
    const int koff[K_] = {-HX - 1, -HX, -HX + 1, -1, 0, 1, HX - 1, HX, HX + 1};

    float dot[K_], psq[K_];
#pragma unroll
    for (int k = 0; k < K_; ++k) { dot[k] = 0.f; psq[k] = 0.f; }
    float fsq = 0.f;

    // Pass 1: per-k stats over this half's 2 octs; b128 taps, fdot2 f32-accum
#pragma unroll
    for (int j = 0; j < 2; ++j) {
        const int oct = 2 * half + j;
        h8v fq = fe8[j];
        h2v fA0 = __builtin_shufflevector(fq, fq, 0, 1);
        h2v fA1 = __builtin_shufflevector(fq, fq, 2, 3);
        h2v fA2 = __builtin_shufflevector(fq, fq, 4, 5);
        h2v fA3 = __builtin_shufflevector(fq, fq, 6, 7);
        fsq = dot2(fA0, fA0, fsq);
        fsq = dot2(fA1, fA1, fsq);
        fsq = dot2(fA2, fA2, fsq);
        fsq = dot2(fA3, fA3, fsq);
        const h8v* fubase = &lds8[oct * HCH + hc];
#pragma unroll
        for (int k = 0; k < K_; ++k) {
            h8v p8 = fubase[koff[k]];
            h2v p0 = __builtin_shufflevector(p8, p8, 0, 1);
            h2v p1 = __builtin_shufflevector(p8, p8, 2, 3);
            h2v p2 = __builtin_shufflevector(p8, p8, 4, 5);
            h2v p3 = __builtin_shufflevector(p8, p8, 6, 7);
            dot[k] = dot2(p0, fA0, dot[k]);
            dot[k] = dot2(p1, fA1, dot[k]);
            dot[k] = dot2(p2, fA2, dot[k]);
            dot[k] = dot2(p3, fA3, dot[k]);
            psq[k] = dot2(p0, p0, psq[k]);
            psq[k] = dot2(p1, p1, psq[k]);
            psq[k] = dot2(p2, p2, psq[k]);
            psq[k] = dot2(p3, p3, psq[k]);
        }
    }

    // combine halves: lanes l and l^32 hold the two channel-halves of one pixel
#pragma unroll
    for (int k = 0; k < K_; ++k) {
        dot[k] += __shfl_xor(dot[k], 32);
        psq[k] += __shfl_xor(psq[k], 32);
    }
    fsq += __shfl_xor(fsq, 32);

    float nf = fmaxf(sqrtf(fsq), EPS_);
    float cosv[K_], negd[K_];
#pragma unroll
    for (int k = 0; k < K_; ++k) {
        float np = fmaxf(sqrtf(psq[k]), EPS_);
        cosv[k] = __fdividef(dot[k], np * nf);
        float dsq = fmaxf(psq[k] - 2.f * dot[k] + fsq, 0.f);   // ||p-f||^2
        negd[k] = -sqrtf(dsq);
    }

    float m1 = cosv[0], m2 = negd[0];
#pragma unroll
    for (int k = 1; k < K_; ++k) { m1 = fmaxf(m1, cosv[k]); m2 = fmaxf(m2, negd[k]); }
    float s1 = 0.f, s2 = 0.f, e1[K_], e2[K_];
#pragma unroll
    for (int k = 0; k < K_; ++k) {
        e1[k] = __expf(cosv[k] - m1);
        e2[k] = __expf(negd[k] - m2);
        s1 += e1[k]; s2 += e2[k];
    }
    float r1 = __fdividef(0.5f, s1), r2 = __fdividef(0.5f, s2);
    h2v w2[K_];
#pragma unroll
    for (int k = 0; k < K_; ++k) {
        float wk = fmaf(e1[k], r1, e2[k] * r2);
        _Float16 wh = (_Float16)wk;
        h2v tmp = {wh, wh};
        w2[k] = tmp;
    }

    // Pass 2: packed weighted gather (b128 taps) + f16 residual from regs
#pragma unroll
    for (int j = 0; j < 2; ++j) {
        const int oct = 2 * half + j;
        const h8v* fubase = &lds8[oct * HCH + hc];
        h2v a0 = {(_Float16)0, (_Float16)0};
        h2v a1 = a0, a2 = a0, a3 = a0;
#pragma unroll
        for (int k = 0; k < K_; ++k) {
            h8v p8 = fubase[koff[k]];
            a0 += w2[k] * __builtin_shufflevector(p8, p8, 0, 1);
            a1 += w2[k] * __builtin_shufflevector(p8, p8, 2, 3);
            a2 += w2[k] * __builtin_shufflevector(p8, p8, 4, 5);
            a3 += w2[k] * __builtin_shufflevector(p8, p8, 6, 7);
        }
        h8v fq = fe8[j];
        const int cg = oct * 8;
        out[pxoff + (cg + 0) * HW_] = (float)(fq[0] + a0[0]);
        out[pxoff + (cg + 1) * HW_] = (float)(fq[1] + a0[1]);
        out[pxoff + (cg + 2) * HW_] = (float)(fq[2] + a1[0]);
        out[pxoff + (cg + 3) * HW_] = (float)(fq[3] + a1[1]);
        out[pxoff + (cg + 4) * HW_] = (float)(fq[4] + a2[0]);
        out[pxoff + (cg + 5) * HW_] = (float)(fq[5] + a2[1]);
        out[pxoff + (cg + 6) * HW_] = (float)(fq[6] + a3[0]);
        out[pxoff + (cg + 7) * HW_] = (float)(fq[7] + a3[1]);
    }
}

extern "C" void kernel_launch(void* const* d_in, const int* in_sizes, int n_in,
                              void* d_out, int out_size, void* d_ws, size_t ws_size,
                              hipStream_t stream) {
    const float* fe = (const float*)d_in[0];
    const float* fu = (const float*)d_in[1];
    float* out = (float*)d_out;
    dim3 grid((W_ / TX) * (H_ / TY) * B_), block(256);  // 2048 blocks = 8/CU exact
    hipLaunchKernelGGL(asfr_kernel, grid, block, 0, stream, fe, fu, out);
}

// Round 21
// 31.693 us; speedup vs baseline: 1.1735x; 1.1735x over previous
//
#include <hip/hip_runtime.h>
#include <math.h>

#define B_ 4
#define C_ 32
#define H_ 256
#define W_ 256
#define HW_ (H_ * W_)
#define K_ 9
#define TX 32
#define TY 4
#define HX 34              // TX + 2
#define HY 6               // TY + 2
#define HCH (HX * HY)      // 204 real halo positions; padded to 256/oct in LDS
#define NOCT 4
#define EPS_ 1e-12f

typedef _Float16 h2v __attribute__((ext_vector_type(2)));
typedef _Float16 h8v __attribute__((ext_vector_type(8)));

#if defined(__has_builtin)
#if __has_builtin(__builtin_amdgcn_fdot2)
#define HAVE_FDOT2 1
#endif
#if __has_builtin(__builtin_amdgcn_cvt_pkrtz)
#define HAVE_PKRTZ 1
#endif
#endif

static __device__ __forceinline__ h2v pk2(float a, float b) {
#if defined(HAVE_PKRTZ)
    return __builtin_bit_cast(h2v, __builtin_amdgcn_cvt_pkrtz(a, b));
#else
    h2v r = {(_Float16)a, (_Float16)b};
    return r;
#endif
}

static __device__ __forceinline__ float dot2(h2v a, h2v b, float c) {
#if defined(HAVE_FDOT2)
    return __builtin_amdgcn_fdot2(a, b, c, false);
#else
    return c + (float)a[0] * (float)b[0] + (float)a[1] * (float)b[1];
#endif
}

// FINAL (= R16/R19, best clean configuration: 32.07-32.11 us, reproduced).
// 256 thr, 32x4 tile, 2 thr/pixel (channel halves), grid 2048 = exactly
// 8 blocks/CU. fu halo staged as oct-major h8 f16 (padded 204->256/oct,
// 16 KB LDS, no divergent tail); all taps ds_read_b128 (8 ch/read); fdot2
// f32-accum; fe held as 2xh8 regs across the softmax; MLP-maximized stage.
// Rejected (measured): R15 2-tile pipeline (occupancy trade, 34.1), R17/R18
// sq-table (allocator spill, 34.7/36.3), R20 64x2 burst reshape (37.2 —
// stage is VMEM-issue/latency bound, not DRAM-burst bound), R5/R9 big blocks
// (launch-bounds spill). Effective 2.9 TB/s on 94 MB ~= plateau for the
// channel-strided unfold gather. Spill sentinel: WRITE_SIZE == 32768 KB.
__global__ __launch_bounds__(256, 6) void asfr_kernel(const float* __restrict__ fe,
                                                      const float* __restrict__ fu,
                                                      float* __restrict__ out) {
    __shared__ h8v lds8[NOCT * 256];   // 16 KB, padded halo
    const int t = threadIdx.x;
    const int bx = blockIdx.x & 7;           // W_/TX = 8
    const int by = (blockIdx.x >> 3) & 63;   // H_/TY = 64
    const int b  = blockIdx.x >> 9;
    const int w0 = bx * TX, h0 = by * TY;

    const int x = t & 31;
    const int half = (t >> 5) & 1;
    const int y = t >> 6;
    const int c0 = half << 4;
    const int pxoff = b * (C_ * HW_) + (h0 + y) * W_ + (w0 + x);

    // staging descriptors: 4 uniform h8-units (oct = u>>8, pos = u&255)
    int goff[4];
    float msk[4];
#pragma unroll
    for (int j = 0; j < 4; ++j) {
        int u = t + j * 256;
        int oct = u >> 8;
        int pos = u & 255;
        int pp = pos < HCH ? pos : HCH - 1;      // clamp pad lanes to a safe addr
        int r = pp / HX;
        int col = pp - r * HX;
        int hh = h0 - 1 + r;
        int ww = w0 - 1 + col;
        bool ok = (pos < HCH) && ((unsigned)hh < (unsigned)H_) && ((unsigned)ww < (unsigned)W_);
        int hcl = hh < 0 ? 0 : (hh > H_ - 1 ? H_ - 1 : hh);
        int wcl = ww < 0 ? 0 : (ww > W_ - 1 ? W_ - 1 : ww);
        goff[j] = (oct * 8) * HW_ + hcl * W_ + wcl;
        msk[j] = ok ? 1.f : 0.f;
    }

    // fe loads + immediate h8 conversion (fv dies before fu loads peak)
    float fv[16];
#pragma unroll
    for (int cc = 0; cc < 16; ++cc) fv[cc] = fe[pxoff + (c0 + cc) * HW_];
    h8v fe8[2];
#pragma unroll
    for (int j = 0; j < 2; ++j)
#pragma unroll
        for (int c = 0; c < 4; ++c) {
            h2v p = pk2(fv[8 * j + 2 * c], fv[8 * j + 2 * c + 1]);
            fe8[j][2 * c] = p[0];
            fe8[j][2 * c + 1] = p[1];
        }

    // ALL fu staging loads in flight, then convert+write
    const float* fub = fu + b * (C_ * HW_);
    float s[32];
#pragma unroll
    for (int j = 0; j < 4; ++j)
#pragma unroll
        for (int c = 0; c < 8; ++c) s[8 * j + c] = fub[goff[j] + c * HW_];
#pragma unroll
    for (int j = 0; j < 4; ++j) {
        h8v hv;
#pragma unroll
        for (int c = 0; c < 4; ++c) {
            h2v p = pk2(s[8 * j + 2 * c] * msk[j], s[8 * j + 2 * c + 1] * msk[j]);
            hv[2 * c] = p[0];
            hv[2 * c + 1] = p[1];
        }
        lds8[t + j * 256] = hv;
    }
    __syncthreads();

    const int hc = (y + 1) * HX + (x + 1);
    const int koff[K_] = {-HX - 1, -HX, -HX + 1, -1, 0, 1, HX - 1, HX, HX + 1};

    float dot[K_], psq[K_];
#pragma unroll
    for (int k = 0; k < K_; ++k) { dot[k] = 0.f; psq[k] = 0.f; }
    float fsq = 0.f;

    // Pass 1: per-k stats over this half's 2 octs; b128 taps, fdot2 f32-accum
#pragma unroll
    for (int j = 0; j < 2; ++j) {
        const int oct = 2 * half + j;
        h8v fq = fe8[j];
        h2v fA0 = __builtin_shufflevector(fq, fq, 0, 1);
        h2v fA1 = __builtin_shufflevector(fq, fq, 2, 3);
        h2v fA2 = __builtin_shufflevector(fq, fq, 4, 5);
        h2v fA3 = __builtin_shufflevector(fq, fq, 6, 7);
        fsq = dot2(fA0, fA0, fsq);
        fsq = dot2(fA1, fA1, fsq);
        fsq = dot2(fA2, fA2, fsq);
        fsq = dot2(fA3, fA3, fsq);
        const h8v* fubase = &lds8[(oct << 8) + hc];
#pragma unroll
        for (int k = 0; k < K_; ++k) {
            h8v p8 = fubase[koff[k]];
            h2v p0 = __builtin_shufflevector(p8, p8, 0, 1);
            h2v p1 = __builtin_shufflevector(p8, p8, 2, 3);
            h2v p2 = __builtin_shufflevector(p8, p8, 4, 5);
            h2v p3 = __builtin_shufflevector(p8, p8, 6, 7);
            dot[k] = dot2(p0, fA0, dot[k]);
            dot[k] = dot2(p1, fA1, dot[k]);
            dot[k] = dot2(p2, fA2, dot[k]);
            dot[k] = dot2(p3, fA3, dot[k]);
            psq[k] = dot2(p0, p0, psq[k]);
            psq[k] = dot2(p1, p1, psq[k]);
            psq[k] = dot2(p2, p2, psq[k]);
            psq[k] = dot2(p3, p3, psq[k]);
        }
    }

    // combine halves: lanes l and l^32 hold the two channel-halves of one pixel
#pragma unroll
    for (int k = 0; k < K_; ++k) {
        dot[k] += __shfl_xor(dot[k], 32);
        psq[k] += __shfl_xor(psq[k], 32);
    }
    fsq += __shfl_xor(fsq, 32);

    float nf = fmaxf(sqrtf(fsq), EPS_);
    float cosv[K_], negd[K_];
#pragma unroll
    for (int k = 0; k < K_; ++k) {
        float np = fmaxf(sqrtf(psq[k]), EPS_);
        cosv[k] = __fdividef(dot[k], np * nf);
        float dsq = fmaxf(psq[k] - 2.f * dot[k] + fsq, 0.f);   // ||p-f||^2
        negd[k] = -sqrtf(dsq);
    }

    float m1 = cosv[0], m2 = negd[0];
#pragma unroll
    for (int k = 1; k < K_; ++k) { m1 = fmaxf(m1, cosv[k]); m2 = fmaxf(m2, negd[k]); }
    float s1 = 0.f, s2 = 0.f, e1[K_], e2[K_];
#pragma unroll
    for (int k = 0; k < K_; ++k) {
        e1[k] = __expf(cosv[k] - m1);
        e2[k] = __expf(negd[k] - m2);
        s1 += e1[k]; s2 += e2[k];
    }
    float r1 = __fdividef(0.5f, s1), r2 = __fdividef(0.5f, s2);
    h2v w2[K_];
#pragma unroll
    for (int k = 0; k < K_; ++k) {
        float wk = fmaf(e1[k], r1, e2[k] * r2);
        _Float16 wh = (_Float16)wk;
        h2v tmp = {wh, wh};
        w2[k] = tmp;
    }

    // Pass 2: packed weighted gather (b128 taps) + f16 residual from regs
#pragma unroll
    for (int j = 0; j < 2; ++j) {
        const int oct = 2 * half + j;
        const h8v* fubase = &lds8[(oct << 8) + hc];
        h2v a0 = {(_Float16)0, (_Float16)0};
        h2v a1 = a0, a2 = a0, a3 = a0;
#pragma unroll
        for (int k = 0; k < K_; ++k) {
            h8v p8 = fubase[koff[k]];
            a0 += w2[k] * __builtin_shufflevector(p8, p8, 0, 1);
            a1 += w2[k] * __builtin_shufflevector(p8, p8, 2, 3);
            a2 += w2[k] * __builtin_shufflevector(p8, p8, 4, 5);
            a3 += w2[k] * __builtin_shufflevector(p8, p8, 6, 7);
        }
        h8v fq = fe8[j];
        const int cg = oct * 8;
        out[pxoff + (cg + 0) * HW_] = (float)(fq[0] + a0[0]);
        out[pxoff + (cg + 1) * HW_] = (float)(fq[1] + a0[1]);
        out[pxoff + (cg + 2) * HW_] = (float)(fq[2] + a1[0]);
        out[pxoff + (cg + 3) * HW_] = (float)(fq[3] + a1[1]);
        out[pxoff + (cg + 4) * HW_] = (float)(fq[4] + a2[0]);
        out[pxoff + (cg + 5) * HW_] = (float)(fq[5] + a2[1]);
        out[pxoff + (cg + 6) * HW_] = (float)(fq[6] + a3[0]);
        out[pxoff + (cg + 7) * HW_] = (float)(fq[7] + a3[1]);
    }
}

extern "C" void kernel_launch(void* const* d_in, const int* in_sizes, int n_in,
                              void* d_out, int out_size, void* d_ws, size_t ws_size,
                              hipStream_t stream) {
    const float* fe = (const float*)d_in[0];
    const float* fu = (const float*)d_in[1];
    float* out = (float*)d_out;
    dim3 grid((W_ / TX) * (H_ / TY) * B_), block(256);  // 2048 blocks = 8/CU exact
    hipLaunchKernelGGL(asfr_kernel, grid, block, 0, stream, fe, fu, out);
}